// Round 7
// baseline (407.140 us; speedup 1.0000x reference)
//
#include <hip/hip_runtime.h>
#include <math.h>

#define B_ 4
#define T_ 2048
#define C_ 768
#define DK_ 96
#define NA_ 8
#define M_ (B_*T_)      /* 8192 */
#define K2_ (2*C_)      /* 1536 */
#define NCH_ 256        /* EMA chunks per batch */
#define CK_ 8           /* EMA chunk len == tile row-chunk */

typedef __attribute__((ext_vector_type(8))) _Float16 half8;
typedef __attribute__((ext_vector_type(4))) _Float16 half4;
typedef __attribute__((ext_vector_type(4))) float floatx4;

#define AS1 __attribute__((address_space(1)))
#define AS3 __attribute__((address_space(3)))

// fast activations: v_exp_f32 + v_rcp_f32 (confirmed win: s3 VALUBusy 25->21.5)
__device__ __forceinline__ float sigm(float x){
  return __builtin_amdgcn_rcpf(1.f + __expf(-x));
}
__device__ __forceinline__ float ftanh(float x){
  return 1.f - 2.f*__builtin_amdgcn_rcpf(1.f + __expf(2.f*x));
}
__device__ __forceinline__ unsigned enc_max(float f){
  unsigned i = __float_as_uint(f);
  return (i & 0x80000000u) ? ~i : (i | 0x80000000u);
}
__device__ __forceinline__ float dec_max(unsigned u){
  unsigned i = (u & 0x80000000u) ? (u & 0x7FFFFFFFu) : ~u;
  return __uint_as_float(i);
}
__device__ __forceinline__ void gld16(const _Float16* g, _Float16* l){
  __builtin_amdgcn_global_load_lds((const AS1 unsigned int*)g, (AS3 unsigned int*)l, 16, 0, 0);
}

// 2-level chunk-prefix scan: 256 threads = 16 cols x 16 groups of 16 chunks.
__device__ __forceinline__ void scan2l(const float* __restrict__ S, float* __restrict__ H,
                                       int b, int cg0, float aCK, float A16,
                                       float* __restrict__ carry /* [16*17] */){
  int tid = threadIdx.x;
  int cl = tid & 15, g = tid >> 4;
  int c = cg0 + cl;
  float sv[16];
  float cv = 0.f;
  #pragma unroll
  for (int j = 0; j < 16; ++j){
    sv[j] = S[(size_t)(b*NCH_ + g*16 + j)*C_ + c];
    cv = aCK*cv + sv[j];
  }
  carry[cl*17 + g] = cv;
  __syncthreads();
  float h = 0.f;
  for (int gp = 0; gp < g; ++gp) h = A16*h + carry[cl*17 + gp];
  #pragma unroll
  for (int j = 0; j < 16; ++j){
    H[(size_t)(b*NCH_ + g*16 + j)*C_ + c] = h;
    h = aCK*h + sv[j];
  }
}

// ---------------- L1: cast x -> xh + gate chunk sums ----------------
__global__ __launch_bounds__(192) void k_castx(
    const float* __restrict__ x, const float* __restrict__ tau,
    _Float16* __restrict__ xh, float* __restrict__ Sg){
  float al = expf(-log1pf(expf(tau[0])));
  int blk = blockIdx.x, b = blk >> 8, ch = blk & (NCH_-1);
  int t0 = b*T_ + ch*CK_;
  int c4 = threadIdx.x;
  float s0=0.f,s1=0.f,s2=0.f,s3=0.f;
  #pragma unroll
  for (int t = 0; t < CK_; ++t){
    float4 v = *(const float4*)(x + (size_t)(t0+t)*C_ + c4*4);
    half4 h = { (_Float16)v.x,(_Float16)v.y,(_Float16)v.z,(_Float16)v.w };
    *(half4*)(xh + (size_t)(t0+t)*C_ + c4*4) = h;
    s0 = al*s0 + v.x; s1 = al*s1 + v.y; s2 = al*s2 + v.z; s3 = al*s3 + v.w;
  }
  float4 sv = { s0,s1,s2,s3 };
  *(float4*)(Sg + (size_t)blk*C_ + c4*4) = sv;
}

// ---------------- L2: weight casts + cgE init + anchors + gate chunk-prefix ----------------
#define NB0 4608   /* wall quads */
#define NB1 4896   /* + wqk/cgE (288) */
#define NB2 4920   /* + anchor (24) */
#define NB3 5112   /* + p2_gate 2-level scan (192) */
__global__ __launch_bounds__(256) void k_prep(
    const float* __restrict__ x,
    const float* __restrict__ Wp, const float* __restrict__ Wfast,
    const float* __restrict__ Wslow, const float* __restrict__ Wsoma,
    const float* __restrict__ Wxf, const float* __restrict__ Wxs,
    const float* __restrict__ Wcf, const float* __restrict__ Wcs,
    const float* __restrict__ Wq, const float* __restrict__ Wk,
    const float* __restrict__ Wanc, const float* __restrict__ banc,
    const float* __restrict__ ascl, const float* __restrict__ tau_gate,
    const float* __restrict__ Sg,
    _Float16* __restrict__ wall, _Float16* __restrict__ wqk,
    unsigned* __restrict__ cgE, float* __restrict__ Hg, float* __restrict__ dlt)
{
  __shared__ float xs[NA_*C_];
  __shared__ float part[NA_*128];
  __shared__ float carry[16*17];
  int blk = blockIdx.x, tid = threadIdx.x;
  if (blk < NB0){
    int i = blk*256 + tid;
    const int per = (C_*C_)/4;
    int s = i / per, j = i - s*per;
    const float* src = s==0?Wp : s==1?Wfast : s==2?Wslow : s==3?Wsoma
                     : s==4?Wxf : s==5?Wxs : s==6?Wcf : Wcs;
    float4 v = ((const float4*)src)[j];
    half4 h = { (_Float16)v.x, (_Float16)v.y, (_Float16)v.z, (_Float16)v.w };
    ((half4*)wall)[(size_t)s*per + j] = h;
  } else if (blk < NB1){
    int sub = blk - NB0;
    if (sub >= 256){ cgE[(sub-256)*256 + tid] = 0u; return; }
    const float* src = (sub < 96) ? Wq + (size_t)sub*C_
                     : (sub < 192 ? Wk + (size_t)(sub-96)*C_ : nullptr);
    #pragma unroll
    for (int k = 0; k < 3; ++k){
      int c = tid + k*256;
      wqk[(size_t)sub*C_ + c] = src ? (_Float16)src[c] : (_Float16)0.f;
    }
  } else if (blk < NB2){
    int ab = blk - NB1;              // 0..23
    int ct = ab % 6, b = ab / 6;
    for (int i = tid; i < NA_*C_; i += 256){
      int n = i / C_, c = i - n*C_;
      xs[i] = x[(size_t)(b*T_ + n*(T_/NA_))*C_ + c];
    }
    __syncthreads();
    int col = ct*128 + (tid & 127), kh = tid >> 7;
    float acc[NA_] = {0,0,0,0,0,0,0,0};
    const float* wrow = Wanc + (size_t)col*C_ + kh*384;
    const float* xk = xs + kh*384;
    for (int k = 0; k < 384; ++k){
      float wv = wrow[k];
      #pragma unroll
      for (int n = 0; n < NA_; ++n) acc[n] += xk[n*C_ + k]*wv;
    }
    if (kh){
      #pragma unroll
      for (int n = 0; n < NA_; ++n) part[n*128 + (tid & 127)] = acc[n];
    }
    __syncthreads();
    if (!kh){
      float d = 0.f;
      float bv = banc[col];
      #pragma unroll
      for (int n = 0; n < NA_; ++n){
        float a = ftanh(acc[n] + part[n*128 + (tid & 127)] + bv);
        d += sigm(ascl[n]) * a;
      }
      dlt[(size_t)b*C_ + col] = d;
    }
  } else {
    // gate chunk-prefix, 2-level scan (needs Sg from L1)
    int sub = blk - NB2;             // 0..191
    int b = sub / 48, cg0 = (sub - b*48)*16;
    float sp = log1pf(expf(tau_gate[0]));
    scan2l(Sg, Hg, b, cg0, expf(-8.f*sp), expf(-128.f*sp), carry);
  }
}

// ---------------- fast/slow chunk-prefix: 2-level scan ----------------
__global__ __launch_bounds__(256) void k_p2_fs(const float* __restrict__ Sf, const float* __restrict__ Ss,
                                               float* __restrict__ Hf, float* __restrict__ Hs,
                                               const float* __restrict__ tf, const float* __restrict__ ts){
  __shared__ float carry[16*17];
  int blk = blockIdx.x;
  int which = blk / (B_*48);
  int rem = blk - which*(B_*48);
  int b = rem / 48, cg0 = (rem - b*48)*16;
  float sp = log1pf(expf(which ? ts[0] : tf[0]));
  scan2l(which ? Ss : Sf, which ? Hs : Hf, b, cg0, expf(-8.f*sp), expf(-128.f*sp), carry);
}

// ---------------- gate-EMA pass3: stream -> gate buffer ----------------
// 2 chunks/block, 8 cols/thread -> half8 (16B) loads/stores (G13).
__global__ __launch_bounds__(192) void k_gate_p3(
    const _Float16* __restrict__ xh, const float* __restrict__ H,
    const float* __restrict__ tau, _Float16* __restrict__ gate){
  float al = expf(-log1pf(expf(tau[0])));
  int tid = threadIdx.x;
  int half = tid / 96, ct = tid - half*96;
  int g = blockIdx.x*2 + half;                 // chunk 0..1023
  int b = g >> 8, ch = g & (NCH_-1);
  int c0 = ct*8;
  int t0 = b*T_ + ch*CK_;
  float4 h0a = *(const float4*)(H + (size_t)g*C_ + c0);
  float4 h0b = *(const float4*)(H + (size_t)g*C_ + c0 + 4);
  float gv[8] = { h0a.x,h0a.y,h0a.z,h0a.w, h0b.x,h0b.y,h0b.z,h0b.w };
  #pragma unroll
  for (int t = 0; t < CK_; ++t){
    half8 v = *(const half8*)(xh + (size_t)(t0+t)*C_ + c0);
    half8 o;
    #pragma unroll
    for (int i = 0; i < 8; ++i){
      gv[i] = al*gv[i] + (float)v[i];
      o[i] = (_Float16)gv[i];
    }
    *(half8*)(gate + (size_t)(t0+t)*C_ + c0) = o;
  }
}

// ---------------- fs-EMA pass3: stream -> cf/cs IN PLACE into wgfs ----------------
// 2 chunks/block, 8 cols/thread -> half8 (16B) loads/stores.
__global__ __launch_bounds__(192) void k_fs_p3(
    const _Float16* __restrict__ xph, _Float16* __restrict__ wgfs,
    const float* __restrict__ Hf, const float* __restrict__ Hs,
    const float* __restrict__ tf, const float* __restrict__ ts,
    const unsigned* __restrict__ cgE, const float* __restrict__ dlt){
  float af = expf(-log1pf(expf(tf[0])));
  float as = expf(-log1pf(expf(ts[0])));
  int tid = threadIdx.x;
  int half = tid / 96, ct = tid - half*96;
  int g = blockIdx.x*2 + half;                 // chunk 0..1023
  int b = g >> 8, ch = g & (NCH_-1);
  int c0 = ct*8;
  int t0 = b*T_ + ch*CK_;
  float4 hfa = *(const float4*)(Hf + (size_t)g*C_ + c0);
  float4 hfb = *(const float4*)(Hf + (size_t)g*C_ + c0 + 4);
  float4 hsa = *(const float4*)(Hs + (size_t)g*C_ + c0);
  float4 hsb = *(const float4*)(Hs + (size_t)g*C_ + c0 + 4);
  float4 d4a = *(const float4*)(dlt + (size_t)b*C_ + c0);
  float4 d4b = *(const float4*)(dlt + (size_t)b*C_ + c0 + 4);
  float fv[8] = { hfa.x,hfa.y,hfa.z,hfa.w, hfb.x,hfb.y,hfb.z,hfb.w };
  float ev[8] = { hsa.x,hsa.y,hsa.z,hsa.w, hsb.x,hsb.y,hsb.z,hsb.w };
  float dv[8] = { d4a.x,d4a.y,d4a.z,d4a.w, d4b.x,d4b.y,d4b.z,d4b.w };
  float cgr[CK_];
  #pragma unroll
  for (int t = 0; t < CK_; ++t) cgr[t] = sigm(dec_max(cgE[t0+t]));
  #pragma unroll
  for (int t = 0; t < CK_; ++t){
    size_t rp = (size_t)(t0+t);
    half8 p  = *(const half8*)(xph  + rp*C_  + c0);
    half8 wf = *(const half8*)(wgfs + rp*K2_ + c0);
    half8 ws = *(const half8*)(wgfs + rp*K2_ + C_ + c0);
    float cg = cgr[t];
    half8 of, os;
    #pragma unroll
    for (int i = 0; i < 8; ++i){
      fv[i] = af*fv[i] + (float)p[i]*(float)wf[i];
      ev[i] = as*ev[i] + (float)p[i]*(float)ws[i];
      of[i] = (_Float16)(fv[i]*cg + dv[i]);
      os[i] = (_Float16)(ev[i]*cg + dv[i]);
    }
    *(half8*)(wgfs + rp*K2_ + c0) = of;
    *(half8*)(wgfs + rp*K2_ + C_ + c0) = os;
  }
}

// ---------------- GEMM building blocks (128x128, BK=64, async LDS + XOR swizzle) ----------------
__device__ __forceinline__ void stage_tile(const _Float16* __restrict__ src, int stride,
                                           int r0, int k0, _Float16* lds){
  int tid = threadIdx.x;
  int wave = tid >> 6, lane = tid & 63;
  #pragma unroll
  for (int it = 0; it < 4; ++it){
    int cb = it*256 + wave*64;
    int ck = cb + lane;
    int row = ck >> 3;
    int kp = (ck & 7) ^ (row & 7);
    gld16(src + (size_t)(r0+row)*stride + k0 + kp*8, lds + (size_t)cb*8);
  }
}

__device__ __forceinline__ void mfma_pass(const _Float16* As, const _Float16* Ws, floatx4 acc[4][4]){
  int tid = threadIdx.x;
  int wave = tid >> 6, lane = tid & 63;
  int wr = wave >> 1, wc = wave & 1;
  int lr = lane & 15, lq = lane >> 4;
  #pragma unroll
  for (int ks = 0; ks < 2; ++ks){
    half8 fa[4], fb[4];
    int off = (((ks*4 + lq) ^ (lr & 7)) << 3);
    #pragma unroll
    for (int i = 0; i < 4; ++i){
      fa[i] = *(const half8*)(As + (wr*64 + i*16 + lr)*64 + off);
      fb[i] = *(const half8*)(Ws + (wc*64 + i*16 + lr)*64 + off);
    }
    #pragma unroll
    for (int i = 0; i < 4; ++i)
      #pragma unroll
      for (int j = 0; j < 4; ++j)
        acc[i][j] = __builtin_amdgcn_mfma_f32_16x16x32_f16(fa[i], fb[j], acc[i][j], 0, 0, 0);
  }
}

__device__ __forceinline__ void store_tile_f16(floatx4 acc[4][4], _Float16* __restrict__ out, int ldo,
                                               const float* bias, const float* bias2,
                                               int m0, int n0, int act){
  int tid = threadIdx.x;
  int wave = tid >> 6, lane = tid & 63;
  int wr = wave >> 1, wc = wave & 1;
  int lr = lane & 15, lq = lane >> 4;
  #pragma unroll
  for (int i = 0; i < 4; ++i){
    #pragma unroll
    for (int j = 0; j < 4; ++j){
      int col = n0 + wc*64 + j*16 + lr;
      float bv = 0.f;
      if (bias) bv = (bias2 && col >= C_) ? bias2[col - C_] : bias[col];
      #pragma unroll
      for (int r = 0; r < 4; ++r){
        int rowm = m0 + wr*64 + i*16 + lq*4 + r;
        float z = acc[i][j][r] + bv;
        if (act == 1) z = ftanh(z);
        else if (act == 2) z = sigm(z);
        out[(size_t)rowm*ldo + col] = (_Float16)z;
      }
    }
  }
}

// stage 3: xp (tanh); wg = xh@[Wxf;Wxs] + gate@[Wcf;Wcs] (sigmoid, split-K); q||k
// occ 4: (256,5) tested -> VGPR 48, no occupancy gain, 2x HBM write traffic, +33us. Keep 4.
__global__ __launch_bounds__(256,4) void k_gemm_s3(
    const _Float16* __restrict__ xh, const _Float16* __restrict__ gate,
    const _Float16* __restrict__ wall, const _Float16* __restrict__ wqk,
    const float* __restrict__ bp, const float* __restrict__ bxf, const float* __restrict__ bxs,
    _Float16* __restrict__ xph, _Float16* __restrict__ wgfs, _Float16* __restrict__ qk)
{
  __shared__ _Float16 As[128*64];
  __shared__ _Float16 Ws[128*64];
  const size_t per = (size_t)C_*C_;
  floatx4 acc[4][4] = {};
  int m0 = blockIdx.x * 128;
  int ny = blockIdx.y;
  if (ny < 6){
    for (int k0 = 0; k0 < C_; k0 += 64){
      stage_tile(xh, C_, m0, k0, As);
      stage_tile(wall, C_, ny*128, k0, Ws);              // Wp
      asm volatile("s_waitcnt vmcnt(0)" ::: "memory");
      __syncthreads();
      mfma_pass(As, Ws, acc);
      __syncthreads();
    }
    store_tile_f16(acc, xph, C_, bp, nullptr, m0, ny*128, 1);
  } else if (ny < 18){
    int n0 = (ny-6)*128;
    for (int k0 = 0; k0 < C_; k0 += 64){
      stage_tile(xh, C_, m0, k0, As);
      stage_tile(wall + 4*per, C_, n0, k0, Ws);          // [Wxf; Wxs]
      asm volatile("s_waitcnt vmcnt(0)" ::: "memory");
      __syncthreads();
      mfma_pass(As, Ws, acc);
      __syncthreads();
    }
    for (int k0 = 0; k0 < C_; k0 += 64){
      stage_tile(gate, C_, m0, k0, As);
      stage_tile(wall + 6*per, C_, n0, k0, Ws);          // [Wcf; Wcs]
      asm volatile("s_waitcnt vmcnt(0)" ::: "memory");
      __syncthreads();
      mfma_pass(As, Ws, acc);
      __syncthreads();
    }
    store_tile_f16(acc, wgfs, K2_, bxf, bxs, m0, n0, 2);
  } else {
    int n0 = (ny-18)*128;
    for (int k0 = 0; k0 < C_; k0 += 64){
      stage_tile(xh, C_, m0, k0, As);
      stage_tile(wqk, C_, n0, k0, Ws);
      asm volatile("s_waitcnt vmcnt(0)" ::: "memory");
      __syncthreads();
      mfma_pass(As, Ws, acc);
      __syncthreads();
    }
    store_tile_f16(acc, qk, 256, nullptr, nullptr, m0, n0, 0);
  }
}

// stage 7 merged: y = tanh(xh@Wsoma + bso) * ( gf + bl*(gs - gf) )
// gf = sigm(cf@Wfast+bf), gs = sigm(cs@Wslow+bs). Three sequential K-loop passes
// over one (m,nt) tile; only the blended gate g (32 VGPR packed f16) lives across
// passes -> peak live ~ acc(64)+g(32)+addr < 128 -> occ 4. Saves 50 MB HBM vs
// separate gfb/gsb/somab materialization.
__global__ __launch_bounds__(256,4) void k_gemm_s7y(
    const _Float16* __restrict__ cfs, const _Float16* __restrict__ xh,
    const _Float16* __restrict__ wall,
    const float* __restrict__ bf, const float* __restrict__ bs, const float* __restrict__ bso,
    const float* __restrict__ blendr, _Float16* __restrict__ y)
{
  __shared__ _Float16 As[128*64];
  __shared__ _Float16 Bs[128*64];
  const size_t per = (size_t)C_*C_;
  int m0 = blockIdx.x * 128, nt = blockIdx.y * 128;
  int tid = threadIdx.x;
  int wave = tid >> 6, lane = tid & 63;
  int wr = wave >> 1, wc = wave & 1;
  int lr = lane & 15, lq = lane >> 4;
  float bl = sigm(blendr[0]);
  half4 gp[4][4];

  // pass 0: gf = sigm(cf @ Wfast + bf) -> gp (f16)
  {
    floatx4 acc[4][4] = {};
    for (int k0 = 0; k0 < C_; k0 += 64){
      stage_tile(cfs, K2_, m0, k0, As);
      stage_tile(wall + 1*per, C_, nt, k0, Bs);
      asm volatile("s_waitcnt vmcnt(0)" ::: "memory");
      __syncthreads();
      mfma_pass(As, Bs, acc);
      __syncthreads();
    }
    #pragma unroll
    for (int i = 0; i < 4; ++i)
      #pragma unroll
      for (int j = 0; j < 4; ++j){
        float bv = bf[nt + wc*64 + j*16 + lr];
        half4 h;
        #pragma unroll
        for (int r = 0; r < 4; ++r) h[r] = (_Float16)sigm(acc[i][j][r] + bv);
        gp[i][j] = h;
      }
  }
  // pass 1: g = gf + bl*(sigm(cs @ Wslow + bs) - gf) -> gp (f16, overwrite)
  {
    floatx4 acc[4][4] = {};
    for (int k0 = 0; k0 < C_; k0 += 64){
      stage_tile(cfs + C_, K2_, m0, k0, As);
      stage_tile(wall + 2*per, C_, nt, k0, Bs);
      asm volatile("s_waitcnt vmcnt(0)" ::: "memory");
      __syncthreads();
      mfma_pass(As, Bs, acc);
      __syncthreads();
    }
    #pragma unroll
    for (int i = 0; i < 4; ++i)
      #pragma unroll
      for (int j = 0; j < 4; ++j){
        float bv = bs[nt + wc*64 + j*16 + lr];
        half4 h = gp[i][j];
        #pragma unroll
        for (int r = 0; r < 4; ++r){
          float gf = (float)h[r];
          float gs = sigm(acc[i][j][r] + bv);
          h[r] = (_Float16)(gf + bl*(gs - gf));
        }
        gp[i][j] = h;
      }
  }
  // pass 2: y = tanh(xh @ Wsoma + bso) * g
  {
    floatx4 acc[4][4] = {};
    for (int k0 = 0; k0 < C_; k0 += 64){
      stage_tile(xh, C_, m0, k0, As);
      stage_tile(wall + 3*per, C_, nt, k0, Bs);
      asm volatile("s_waitcnt vmcnt(0)" ::: "memory");
      __syncthreads();
      mfma_pass(As, Bs, acc);
      __syncthreads();
    }
    #pragma unroll
    for (int i = 0; i < 4; ++i)
      #pragma unroll
      for (int j = 0; j < 4; ++j){
        int col = nt + wc*64 + j*16 + lr;
        float bv = bso[col];
        half4 h = gp[i][j];
        #pragma unroll
        for (int r = 0; r < 4; ++r){
          int rowm = m0 + wr*64 + i*16 + lq*4 + r;
          float z = ftanh(acc[i][j][r] + bv) * (float)h[r];
          y[(size_t)rowm*C_ + col] = (_Float16)z;
        }
      }
  }
}

// ---------------- score (544 blocks) + fs_p1 (512 blocks, 2 chunks each) ----------------
#define SLDK 104
__global__ __launch_bounds__(256,3) void k_score_fs(
    const _Float16* __restrict__ qk, unsigned* __restrict__ cgE,
    const _Float16* __restrict__ xp, const _Float16* __restrict__ wgfs,
    const float* __restrict__ tf, const float* __restrict__ ts,
    float* __restrict__ Sf, float* __restrict__ Ss)
{
  __shared__ _Float16 Qs[128*SLDK];
  __shared__ _Float16 Ks[128*SLDK];
  __shared__ float sred[256];
  int idx = blockIdx.x;
  int tid = threadIdx.x;
  if (idx >= 544){
    // ---- fs_p1: 2 chunks/block, 8 cols/thread, half8 loads ----
    if (tid >= 192) return;
    int half = tid / 96, ct = tid - half*96;
    int f = (idx - 544)*2 + half;            // chunk 0..1023
    float af = expf(-log1pf(expf(tf[0])));
    float as = expf(-log1pf(expf(ts[0])));
    int b = f >> 8, ch = f & (NCH_-1);
    int t0 = b*T_ + ch*CK_;
    int c0 = ct*8;
    float fv[8] = {0,0,0,0,0,0,0,0};
    float sv[8] = {0,0,0,0,0,0,0,0};
    #pragma unroll
    for (int t = 0; t < CK_; ++t){
      half8 p  = *(const half8*)(xp + (size_t)(t0+t)*C_ + c0);
      half8 wf = *(const half8*)(wgfs + (size_t)(t0+t)*K2_ + c0);
      half8 ws = *(const half8*)(wgfs + (size_t)(t0+t)*K2_ + C_ + c0);
      #pragma unroll
      for (int i = 0; i < 8; ++i){
        fv[i] = af*fv[i] + (float)p[i]*(float)wf[i];
        sv[i] = as*sv[i] + (float)p[i]*(float)ws[i];
      }
    }
    float4 fa = { fv[0],fv[1],fv[2],fv[3] }, fb = { fv[4],fv[5],fv[6],fv[7] };
    float4 sa = { sv[0],sv[1],sv[2],sv[3] }, sb = { sv[4],sv[5],sv[6],sv[7] };
    *(float4*)(Sf + (size_t)f*C_ + c0)     = fa;
    *(float4*)(Sf + (size_t)f*C_ + c0 + 4) = fb;
    *(float4*)(Ss + (size_t)f*C_ + c0)     = sa;
    *(float4*)(Ss + (size_t)f*C_ + c0 + 4) = sb;
    return;
  }
  // ---- score ----
  int b = idx / 136;
  int p = idx - b*136;
  int ti = (int)((sqrtf(8.f*p + 1.f) - 1.f)*0.5f);
  while ((ti+1)*(ti+2)/2 <= p) ++ti;
  while (ti*(ti+1)/2 > p) --ti;
  int sj = p - ti*(ti+1)/2;

  const _Float16* qg = qk + (size_t)(b*T_ + ti*128)*256;
  const _Float16* kg = qk + (size_t)(b*T_ + sj*128)*256 + 96;
  #pragma unroll
  for (int r = 0; r < 6; ++r){
    int ci = tid + r*256;
    int row = ci / 12, kp = ci % 12;
    *(uint4*)(&Qs[row*SLDK + kp*8]) = *(const uint4*)(qg + (size_t)row*256 + kp*8);
    *(uint4*)(&Ks[row*SLDK + kp*8]) = *(const uint4*)(kg + (size_t)row*256 + kp*8);
  }
  __syncthreads();

  int wave = tid >> 6, lane = tid & 63;
  int wr = wave >> 1, wc = wave & 1;
  int lr = lane & 15, lq = lane >> 4;
  floatx4 acc[4][4] = {};
  #pragma unroll
  for (int ks = 0; ks < 3; ++ks){
    half8 fa[4], fb[4];
    #pragma unroll
    for (int i = 0; i < 4; ++i){
      fa[i] = *(const half8*)(&Qs[(wr*64 + i*16 + lr)*SLDK + ks*32 + lq*8]);
      fb[i] = *(const half8*)(&Ks[(wc*64 + i*16 + lr)*SLDK + ks*32 + lq*8]);
    }
    #pragma unroll
    for (int i = 0; i < 4; ++i)
      #pragma unroll
      for (int j = 0; j < 4; ++j)
        acc[i][j] = __builtin_amdgcn_mfma_f32_16x16x32_f16(fa[i], fb[j], acc[i][j], 0, 0, 0);
  }
  const float scale = 0.10206207f;   // 96^-0.5
  #pragma unroll
  for (int i = 0; i < 4; ++i){
    #pragma unroll
    for (int r = 0; r < 4; ++r){
      int row64 = i*16 + lq*4 + r;
      int tg = ti*128 + wr*64 + row64;
      float v = -3.0e38f;
      #pragma unroll
      for (int j = 0; j < 4; ++j){
        int sg = sj*128 + wc*64 + j*16 + lr;
        if (sg <= tg) v = fmaxf(v, acc[i][j][r]*scale);
      }
      #pragma unroll
      for (int off = 1; off < 16; off <<= 1) v = fmaxf(v, __shfl_xor(v, off, 16));
      if (lr == 0) sred[wr*128 + wc*64 + row64] = v;
    }
  }
  __syncthreads();
  if (wc == 0 && lane < 64){
    int row64 = lane;
    float v = fmaxf(sred[wr*128 + row64], sred[wr*128 + 64 + row64]);
    int tg = ti*128 + wr*64 + row64;
    atomicMax(&cgE[(size_t)b*T_ + tg], enc_max(v));
  }
}

// ---------------- LayerNorm over y: 2 rows/wave, half8 loads ----------------
__global__ __launch_bounds__(256) void k_ln(const _Float16* __restrict__ yb,
                                            const float* __restrict__ g, const float* __restrict__ be,
                                            float* __restrict__ out){
  int wave = threadIdx.x >> 6, lane = threadIdx.x & 63;
  int half = lane >> 5, l32 = lane & 31;
  int row = blockIdx.x*8 + wave*2 + half;
  size_t rb = (size_t)row*C_;
  float v[24];
  float s = 0.f, ss = 0.f;
  #pragma unroll
  for (int w2 = 0; w2 < 3; ++w2){
    size_t o = rb + w2*256 + l32*8;
    half8 y8 = *(const half8*)(yb + o);
    #pragma unroll
    for (int i = 0; i < 8; ++i){
      float yv = (float)y8[i];
      v[w2*8 + i] = yv; s += yv; ss += yv*yv;
    }
  }
  #pragma unroll
  for (int off = 1; off < 32; off <<= 1){ s += __shfl_xor(s, off, 32); ss += __shfl_xor(ss, off, 32); }
  float mu  = s * (1.f/C_);
  float var = ss * (1.f/C_) - mu*mu;
  float inv = rsqrtf(var + 1e-5f);
  #pragma unroll
  for (int w2 = 0; w2 < 3; ++w2){
    int c0 = w2*256 + l32*8;
    float4 oa, ob;
    oa.x = (v[w2*8+0]-mu)*inv*g[c0+0] + be[c0+0];
    oa.y = (v[w2*8+1]-mu)*inv*g[c0+1] + be[c0+1];
    oa.z = (v[w2*8+2]-mu)*inv*g[c0+2] + be[c0+2];
    oa.w = (v[w2*8+3]-mu)*inv*g[c0+3] + be[c0+3];
    ob.x = (v[w2*8+4]-mu)*inv*g[c0+4] + be[c0+4];
    ob.y = (v[w2*8+5]-mu)*inv*g[c0+5] + be[c0+5];
    ob.z = (v[w2*8+6]-mu)*inv*g[c0+6] + be[c0+6];
    ob.w = (v[w2*8+7]-mu)*inv*g[c0+7] + be[c0+7];
    *(float4*)(out + rb + c0)     = oa;
    *(float4*)(out + rb + c0 + 4) = ob;
  }
}

// ---------------- launch ----------------
extern "C" void kernel_launch(void* const* d_in, const int* in_sizes, int n_in,
                              void* d_out, int out_size, void* d_ws, size_t ws_size,
                              hipStream_t stream){
  (void)in_sizes; (void)n_in; (void)out_size;
  const float* x        = (const float*)d_in[0];
  const float* tau_gate = (const float*)d_in[1];
  const float* tau_fast = (const float*)d_in[2];
  const float* tau_slow = (const float*)d_in[3];
  const float* Wp   = (const float*)d_in[4];  const float* bp    = (const float*)d_in[5];
  const float* Wxf  = (const float*)d_in[6];  const float* bxf   = (const float*)d_in[7];
  const float* Wxs  = (const float*)d_in[8];  const float* bxs   = (const float*)d_in[9];
  const float* Wcf  = (const float*)d_in[10]; const float* Wcs   = (const float*)d_in[11];
  const float* Wq   = (const float*)d_in[12]; const float* Wk    = (const float*)d_in[13];
  const float* Wfast= (const float*)d_in[14]; const float* bfast = (const float*)d_in[15];
  const float* Wslow= (const float*)d_in[16]; const float* bslow = (const float*)d_in[17];
  const float* Wsoma= (const float*)d_in[18]; const float* bsoma = (const float*)d_in[19];
  const float* Wanc = (const float*)d_in[20]; const float* banc  = (const float*)d_in[21];
  const float* ascl = (const float*)d_in[22]; const float* blendr= (const float*)d_in[23];
  const float* lng  = (const float*)d_in[24]; const float* lnb   = (const float*)d_in[25];
  float* out = (float*)d_out;

  char* w = (char*)d_ws;
  auto alloc = [&](size_t bytes)->void*{
    void* p = (void*)w; w += (bytes + 255) & ~(size_t)255; return p;
  };
  _Float16* xh    = (_Float16*)alloc((size_t)M_*C_*2);
  _Float16* wall  = (_Float16*)alloc((size_t)8*C_*C_*2);
  _Float16* wqk   = (_Float16*)alloc((size_t)256*C_*2);
  _Float16* xph   = (_Float16*)alloc((size_t)M_*C_*2);
  _Float16* wgfs  = (_Float16*)alloc((size_t)M_*K2_*2);
  _Float16* qk    = (_Float16*)alloc((size_t)M_*256*2);
  _Float16* yb    = (_Float16*)alloc((size_t)M_*C_*2);
  unsigned* cgE   = (unsigned*)alloc((size_t)M_*4);
  float* Sg = (float*)alloc((size_t)B_*NCH_*C_*4);
  float* Hg = (float*)alloc((size_t)B_*NCH_*C_*4);
  float* Ss = (float*)alloc((size_t)B_*NCH_*C_*4);
  float* Hs = (float*)alloc((size_t)B_*NCH_*C_*4);
  float* dlt = (float*)alloc((size_t)B_*C_*4);
  // aliases (stream-ordered reuse):
  _Float16* gate = yb;   // gate consumed by s3 (L4) before s7y (L7) writes yb
  float* Sf = Sg;        // Sg consumed by prep's p2_gate (L2) before score_fs (L5) writes Sf
  float* Hf = Hg;        // Hg consumed by gate_p3 (L3) before p2_fs (L6) writes Hf
  if ((size_t)(w - (char*)d_ws) > ws_size) return;

  // L1: cast x -> xh + gate chunk sums
  k_castx<<<B_*NCH_, 192, 0, stream>>>(x, tau_gate, xh, Sg);
  // L2: weights, cgE, anchors, gate chunk-prefix (2-level scan, hides under bulk casts)
  k_prep<<<NB3, 256, 0, stream>>>(x, Wp, Wfast, Wslow, Wsoma, Wxf, Wxs, Wcf, Wcs, Wq, Wk,
                                  Wanc, banc, ascl, tau_gate, Sg, wall, wqk, cgE, Hg, dlt);
  // L3: gate EMA stream -> gate buffer (2 chunks/block, half8)
  k_gate_p3<<<B_*NCH_/2, 192, 0, stream>>>(xh, Hg, tau_gate, gate);
  // L4: stage 3 (xp + wg split-K + q||k), clean 2-barrier K-loop
  k_gemm_s3<<<dim3(M_/128, 20), 256, 0, stream>>>(xh, gate, wall, wqk,
                                                  bp, bxf, bxs, xph, wgfs, qk);
  // L5: causal max score + fs chunk sums (2 chunks/block, half8)
  k_score_fs<<<544 + B_*NCH_/2, 256, 0, stream>>>(qk, cgE, xph, wgfs, tau_fast, tau_slow, Sf, Ss);
  // L6: fast/slow chunk-prefix (2-level scan, 384 blocks)
  k_p2_fs<<<2*B_*48, 256, 0, stream>>>(Sf, Ss, Hf, Hs, tau_fast, tau_slow);
  // L6.5: fs EMA pass3 — transform wgfs in place to cf||cs (2 chunks/block, half8)
  k_fs_p3<<<B_*NCH_/2, 192, 0, stream>>>(xph, wgfs, Hf, Hs, tau_fast, tau_slow, cgE, dlt);
  // L7: stage 7 merged — y = tanh(soma)*(gf + bl*(gs-gf)) in one kernel (3-pass K-loop)
  k_gemm_s7y<<<dim3(M_/128, 6), 256, 0, stream>>>(wgfs, xh, wall,
                                                  bfast, bslow, bsoma, blendr, yb);
  // L8: LayerNorm over y (2 rows/wave, half8)
  k_ln<<<M_/8, 256, 0, stream>>>(yb, lng, lnb, out);
}

// Round 8
// 317.289 us; speedup vs baseline: 1.2832x; 1.2832x over previous
//
#include <hip/hip_runtime.h>
#include <math.h>

#define B_ 4
#define T_ 2048
#define C_ 768
#define DK_ 96
#define NA_ 8
#define M_ (B_*T_)      /* 8192 */
#define K2_ (2*C_)      /* 1536 */
#define NCH_ 256        /* EMA chunks per batch */
#define CK_ 8           /* EMA chunk len == tile row-chunk */

typedef __attribute__((ext_vector_type(8))) _Float16 half8;
typedef __attribute__((ext_vector_type(4))) _Float16 half4;
typedef __attribute__((ext_vector_type(4))) float floatx4;

#define AS1 __attribute__((address_space(1)))
#define AS3 __attribute__((address_space(3)))

// fast activations: v_exp_f32 + v_rcp_f32 (confirmed win: s3 VALUBusy 25->21.5)
__device__ __forceinline__ float sigm(float x){
  return __builtin_amdgcn_rcpf(1.f + __expf(-x));
}
__device__ __forceinline__ float ftanh(float x){
  return 1.f - 2.f*__builtin_amdgcn_rcpf(1.f + __expf(2.f*x));
}
__device__ __forceinline__ unsigned enc_max(float f){
  unsigned i = __float_as_uint(f);
  return (i & 0x80000000u) ? ~i : (i | 0x80000000u);
}
__device__ __forceinline__ float dec_max(unsigned u){
  unsigned i = (u & 0x80000000u) ? (u & 0x7FFFFFFFu) : ~u;
  return __uint_as_float(i);
}
__device__ __forceinline__ void gld16(const _Float16* g, _Float16* l){
  __builtin_amdgcn_global_load_lds((const AS1 unsigned int*)g, (AS3 unsigned int*)l, 16, 0, 0);
}

// 2-level chunk-prefix scan: 256 threads = 16 cols x 16 groups of 16 chunks.
__device__ __forceinline__ void scan2l(const float* __restrict__ S, float* __restrict__ H,
                                       int b, int cg0, float aCK, float A16,
                                       float* __restrict__ carry /* [16*17] */){
  int tid = threadIdx.x;
  int cl = tid & 15, g = tid >> 4;
  int c = cg0 + cl;
  float sv[16];
  float cv = 0.f;
  #pragma unroll
  for (int j = 0; j < 16; ++j){
    sv[j] = S[(size_t)(b*NCH_ + g*16 + j)*C_ + c];
    cv = aCK*cv + sv[j];
  }
  carry[cl*17 + g] = cv;
  __syncthreads();
  float h = 0.f;
  for (int gp = 0; gp < g; ++gp) h = A16*h + carry[cl*17 + gp];
  #pragma unroll
  for (int j = 0; j < 16; ++j){
    H[(size_t)(b*NCH_ + g*16 + j)*C_ + c] = h;
    h = aCK*h + sv[j];
  }
}

// ---------------- L1: cast x -> xh + gate chunk sums ----------------
__global__ __launch_bounds__(192) void k_castx(
    const float* __restrict__ x, const float* __restrict__ tau,
    _Float16* __restrict__ xh, float* __restrict__ Sg){
  float al = expf(-log1pf(expf(tau[0])));
  int blk = blockIdx.x, b = blk >> 8, ch = blk & (NCH_-1);
  int t0 = b*T_ + ch*CK_;
  int c4 = threadIdx.x;
  float s0=0.f,s1=0.f,s2=0.f,s3=0.f;
  #pragma unroll
  for (int t = 0; t < CK_; ++t){
    float4 v = *(const float4*)(x + (size_t)(t0+t)*C_ + c4*4);
    half4 h = { (_Float16)v.x,(_Float16)v.y,(_Float16)v.z,(_Float16)v.w };
    *(half4*)(xh + (size_t)(t0+t)*C_ + c4*4) = h;
    s0 = al*s0 + v.x; s1 = al*s1 + v.y; s2 = al*s2 + v.z; s3 = al*s3 + v.w;
  }
  float4 sv = { s0,s1,s2,s3 };
  *(float4*)(Sg + (size_t)blk*C_ + c4*4) = sv;
}

// ---------------- L2: weight casts + cgE init + anchors + gate chunk-prefix ----------------
#define NB0 4608   /* wall quads */
#define NB1 4896   /* + wqk/cgE (288) */
#define NB2 4920   /* + anchor (24) */
#define NB3 5112   /* + p2_gate 2-level scan (192) */
__global__ __launch_bounds__(256) void k_prep(
    const float* __restrict__ x,
    const float* __restrict__ Wp, const float* __restrict__ Wfast,
    const float* __restrict__ Wslow, const float* __restrict__ Wsoma,
    const float* __restrict__ Wxf, const float* __restrict__ Wxs,
    const float* __restrict__ Wcf, const float* __restrict__ Wcs,
    const float* __restrict__ Wq, const float* __restrict__ Wk,
    const float* __restrict__ Wanc, const float* __restrict__ banc,
    const float* __restrict__ ascl, const float* __restrict__ tau_gate,
    const float* __restrict__ Sg,
    _Float16* __restrict__ wall, _Float16* __restrict__ wqk,
    unsigned* __restrict__ cgE, float* __restrict__ Hg, float* __restrict__ dlt)
{
  __shared__ float xs[NA_*C_];
  __shared__ float part[NA_*128];
  __shared__ float carry[16*17];
  int blk = blockIdx.x, tid = threadIdx.x;
  if (blk < NB0){
    int i = blk*256 + tid;
    const int per = (C_*C_)/4;
    int s = i / per, j = i - s*per;
    const float* src = s==0?Wp : s==1?Wfast : s==2?Wslow : s==3?Wsoma
                     : s==4?Wxf : s==5?Wxs : s==6?Wcf : Wcs;
    float4 v = ((const float4*)src)[j];
    half4 h = { (_Float16)v.x, (_Float16)v.y, (_Float16)v.z, (_Float16)v.w };
    ((half4*)wall)[(size_t)s*per + j] = h;
  } else if (blk < NB1){
    int sub = blk - NB0;
    if (sub >= 256){ cgE[(sub-256)*256 + tid] = 0u; return; }
    const float* src = (sub < 96) ? Wq + (size_t)sub*C_
                     : (sub < 192 ? Wk + (size_t)(sub-96)*C_ : nullptr);
    #pragma unroll
    for (int k = 0; k < 3; ++k){
      int c = tid + k*256;
      wqk[(size_t)sub*C_ + c] = src ? (_Float16)src[c] : (_Float16)0.f;
    }
  } else if (blk < NB2){
    int ab = blk - NB1;              // 0..23
    int ct = ab % 6, b = ab / 6;
    for (int i = tid; i < NA_*C_; i += 256){
      int n = i / C_, c = i - n*C_;
      xs[i] = x[(size_t)(b*T_ + n*(T_/NA_))*C_ + c];
    }
    __syncthreads();
    int col = ct*128 + (tid & 127), kh = tid >> 7;
    float acc[NA_] = {0,0,0,0,0,0,0,0};
    const float* wrow = Wanc + (size_t)col*C_ + kh*384;
    const float* xk = xs + kh*384;
    for (int k = 0; k < 384; ++k){
      float wv = wrow[k];
      #pragma unroll
      for (int n = 0; n < NA_; ++n) acc[n] += xk[n*C_ + k]*wv;
    }
    if (kh){
      #pragma unroll
      for (int n = 0; n < NA_; ++n) part[n*128 + (tid & 127)] = acc[n];
    }
    __syncthreads();
    if (!kh){
      float d = 0.f;
      float bv = banc[col];
      #pragma unroll
      for (int n = 0; n < NA_; ++n){
        float a = ftanh(acc[n] + part[n*128 + (tid & 127)] + bv);
        d += sigm(ascl[n]) * a;
      }
      dlt[(size_t)b*C_ + col] = d;
    }
  } else {
    // gate chunk-prefix, 2-level scan (needs Sg from L1)
    int sub = blk - NB2;             // 0..191
    int b = sub / 48, cg0 = (sub - b*48)*16;
    float sp = log1pf(expf(tau_gate[0]));
    scan2l(Sg, Hg, b, cg0, expf(-8.f*sp), expf(-128.f*sp), carry);
  }
}

// ---------------- fast/slow chunk-prefix: 2-level scan ----------------
__global__ __launch_bounds__(256) void k_p2_fs(const float* __restrict__ Sf, const float* __restrict__ Ss,
                                               float* __restrict__ Hf, float* __restrict__ Hs,
                                               const float* __restrict__ tf, const float* __restrict__ ts){
  __shared__ float carry[16*17];
  int blk = blockIdx.x;
  int which = blk / (B_*48);
  int rem = blk - which*(B_*48);
  int b = rem / 48, cg0 = (rem - b*48)*16;
  float sp = log1pf(expf(which ? ts[0] : tf[0]));
  scan2l(which ? Ss : Sf, which ? Hs : Hf, b, cg0, expf(-8.f*sp), expf(-128.f*sp), carry);
}

// ---------------- gate-EMA pass3: stream -> gate buffer ----------------
// 2 chunks/block, 8 cols/thread -> half8 (16B) loads/stores (G13).
__global__ __launch_bounds__(192) void k_gate_p3(
    const _Float16* __restrict__ xh, const float* __restrict__ H,
    const float* __restrict__ tau, _Float16* __restrict__ gate){
  float al = expf(-log1pf(expf(tau[0])));
  int tid = threadIdx.x;
  int half = tid / 96, ct = tid - half*96;
  int g = blockIdx.x*2 + half;                 // chunk 0..1023
  int b = g >> 8, ch = g & (NCH_-1);
  int c0 = ct*8;
  int t0 = b*T_ + ch*CK_;
  float4 h0a = *(const float4*)(H + (size_t)g*C_ + c0);
  float4 h0b = *(const float4*)(H + (size_t)g*C_ + c0 + 4);
  float gv[8] = { h0a.x,h0a.y,h0a.z,h0a.w, h0b.x,h0b.y,h0b.z,h0b.w };
  #pragma unroll
  for (int t = 0; t < CK_; ++t){
    half8 v = *(const half8*)(xh + (size_t)(t0+t)*C_ + c0);
    half8 o;
    #pragma unroll
    for (int i = 0; i < 8; ++i){
      gv[i] = al*gv[i] + (float)v[i];
      o[i] = (_Float16)gv[i];
    }
    *(half8*)(gate + (size_t)(t0+t)*C_ + c0) = o;
  }
}

// ---------------- fs-EMA pass3: stream -> cf/cs IN PLACE into wgfs ----------------
// 2 chunks/block, 8 cols/thread -> half8 (16B) loads/stores.
__global__ __launch_bounds__(192) void k_fs_p3(
    const _Float16* __restrict__ xph, _Float16* __restrict__ wgfs,
    const float* __restrict__ Hf, const float* __restrict__ Hs,
    const float* __restrict__ tf, const float* __restrict__ ts,
    const unsigned* __restrict__ cgE, const float* __restrict__ dlt){
  float af = expf(-log1pf(expf(tf[0])));
  float as = expf(-log1pf(expf(ts[0])));
  int tid = threadIdx.x;
  int half = tid / 96, ct = tid - half*96;
  int g = blockIdx.x*2 + half;                 // chunk 0..1023
  int b = g >> 8, ch = g & (NCH_-1);
  int c0 = ct*8;
  int t0 = b*T_ + ch*CK_;
  float4 hfa = *(const float4*)(Hf + (size_t)g*C_ + c0);
  float4 hfb = *(const float4*)(Hf + (size_t)g*C_ + c0 + 4);
  float4 hsa = *(const float4*)(Hs + (size_t)g*C_ + c0);
  float4 hsb = *(const float4*)(Hs + (size_t)g*C_ + c0 + 4);
  float4 d4a = *(const float4*)(dlt + (size_t)b*C_ + c0);
  float4 d4b = *(const float4*)(dlt + (size_t)b*C_ + c0 + 4);
  float fv[8] = { hfa.x,hfa.y,hfa.z,hfa.w, hfb.x,hfb.y,hfb.z,hfb.w };
  float ev[8] = { hsa.x,hsa.y,hsa.z,hsa.w, hsb.x,hsb.y,hsb.z,hsb.w };
  float dv[8] = { d4a.x,d4a.y,d4a.z,d4a.w, d4b.x,d4b.y,d4b.z,d4b.w };
  float cgr[CK_];
  #pragma unroll
  for (int t = 0; t < CK_; ++t) cgr[t] = sigm(dec_max(cgE[t0+t]));
  #pragma unroll
  for (int t = 0; t < CK_; ++t){
    size_t rp = (size_t)(t0+t);
    half8 p  = *(const half8*)(xph  + rp*C_  + c0);
    half8 wf = *(const half8*)(wgfs + rp*K2_ + c0);
    half8 ws = *(const half8*)(wgfs + rp*K2_ + C_ + c0);
    float cg = cgr[t];
    half8 of, os;
    #pragma unroll
    for (int i = 0; i < 8; ++i){
      fv[i] = af*fv[i] + (float)p[i]*(float)wf[i];
      ev[i] = as*ev[i] + (float)p[i]*(float)ws[i];
      of[i] = (_Float16)(fv[i]*cg + dv[i]);
      os[i] = (_Float16)(ev[i]*cg + dv[i]);
    }
    *(half8*)(wgfs + rp*K2_ + c0) = of;
    *(half8*)(wgfs + rp*K2_ + C_ + c0) = os;
  }
}

// ---------------- GEMM building blocks (128x128, BK=64, async LDS + XOR swizzle) ----------------
__device__ __forceinline__ void stage_tile(const _Float16* __restrict__ src, int stride,
                                           int r0, int k0, _Float16* lds){
  int tid = threadIdx.x;
  int wave = tid >> 6, lane = tid & 63;
  #pragma unroll
  for (int it = 0; it < 4; ++it){
    int cb = it*256 + wave*64;
    int ck = cb + lane;
    int row = ck >> 3;
    int kp = (ck & 7) ^ (row & 7);
    gld16(src + (size_t)(r0+row)*stride + k0 + kp*8, lds + (size_t)cb*8);
  }
}

__device__ __forceinline__ void mfma_pass(const _Float16* As, const _Float16* Ws, floatx4 acc[4][4]){
  int tid = threadIdx.x;
  int wave = tid >> 6, lane = tid & 63;
  int wr = wave >> 1, wc = wave & 1;
  int lr = lane & 15, lq = lane >> 4;
  #pragma unroll
  for (int ks = 0; ks < 2; ++ks){
    half8 fa[4], fb[4];
    int off = (((ks*4 + lq) ^ (lr & 7)) << 3);
    #pragma unroll
    for (int i = 0; i < 4; ++i){
      fa[i] = *(const half8*)(As + (wr*64 + i*16 + lr)*64 + off);
      fb[i] = *(const half8*)(Ws + (wc*64 + i*16 + lr)*64 + off);
    }
    #pragma unroll
    for (int i = 0; i < 4; ++i)
      #pragma unroll
      for (int j = 0; j < 4; ++j)
        acc[i][j] = __builtin_amdgcn_mfma_f32_16x16x32_f16(fa[i], fb[j], acc[i][j], 0, 0, 0);
  }
}

__device__ __forceinline__ void store_tile_f16(floatx4 acc[4][4], _Float16* __restrict__ out, int ldo,
                                               const float* bias, const float* bias2,
                                               int m0, int n0, int act){
  int tid = threadIdx.x;
  int wave = tid >> 6, lane = tid & 63;
  int wr = wave >> 1, wc = wave & 1;
  int lr = lane & 15, lq = lane >> 4;
  #pragma unroll
  for (int i = 0; i < 4; ++i){
    #pragma unroll
    for (int j = 0; j < 4; ++j){
      int col = n0 + wc*64 + j*16 + lr;
      float bv = 0.f;
      if (bias) bv = (bias2 && col >= C_) ? bias2[col - C_] : bias[col];
      #pragma unroll
      for (int r = 0; r < 4; ++r){
        int rowm = m0 + wr*64 + i*16 + lq*4 + r;
        float z = acc[i][j][r] + bv;
        if (act == 1) z = ftanh(z);
        else if (act == 2) z = sigm(z);
        out[(size_t)rowm*ldo + col] = (_Float16)z;
      }
    }
  }
}

// stage 3: xp (tanh); wg = xh@[Wxf;Wxs] + gate@[Wcf;Wcs] (sigmoid, split-K); q||k
// occ 4: (256,5) tested -> VGPR 48, no occupancy gain, 2x HBM write traffic, +33us. Keep 4.
// s7y merge tested (r7): VGPR spill (131MB scratch W) + 384-block grid starvation; A-tile
// re-reads negate the write savings even unspilled. Keep separate s7 + ln.
__global__ __launch_bounds__(256,4) void k_gemm_s3(
    const _Float16* __restrict__ xh, const _Float16* __restrict__ gate,
    const _Float16* __restrict__ wall, const _Float16* __restrict__ wqk,
    const float* __restrict__ bp, const float* __restrict__ bxf, const float* __restrict__ bxs,
    _Float16* __restrict__ xph, _Float16* __restrict__ wgfs, _Float16* __restrict__ qk)
{
  __shared__ _Float16 As[128*64];
  __shared__ _Float16 Ws[128*64];
  const size_t per = (size_t)C_*C_;
  floatx4 acc[4][4] = {};
  int m0 = blockIdx.x * 128;
  int ny = blockIdx.y;
  if (ny < 6){
    for (int k0 = 0; k0 < C_; k0 += 64){
      stage_tile(xh, C_, m0, k0, As);
      stage_tile(wall, C_, ny*128, k0, Ws);              // Wp
      asm volatile("s_waitcnt vmcnt(0)" ::: "memory");
      __syncthreads();
      mfma_pass(As, Ws, acc);
      __syncthreads();
    }
    store_tile_f16(acc, xph, C_, bp, nullptr, m0, ny*128, 1);
  } else if (ny < 18){
    int n0 = (ny-6)*128;
    for (int k0 = 0; k0 < C_; k0 += 64){
      stage_tile(xh, C_, m0, k0, As);
      stage_tile(wall + 4*per, C_, n0, k0, Ws);          // [Wxf; Wxs]
      asm volatile("s_waitcnt vmcnt(0)" ::: "memory");
      __syncthreads();
      mfma_pass(As, Ws, acc);
      __syncthreads();
    }
    for (int k0 = 0; k0 < C_; k0 += 64){
      stage_tile(gate, C_, m0, k0, As);
      stage_tile(wall + 6*per, C_, n0, k0, Ws);          // [Wcf; Wcs]
      asm volatile("s_waitcnt vmcnt(0)" ::: "memory");
      __syncthreads();
      mfma_pass(As, Ws, acc);
      __syncthreads();
    }
    store_tile_f16(acc, wgfs, K2_, bxf, bxs, m0, n0, 2);
  } else {
    int n0 = (ny-18)*128;
    for (int k0 = 0; k0 < C_; k0 += 64){
      stage_tile(xh, C_, m0, k0, As);
      stage_tile(wqk, C_, n0, k0, Ws);
      asm volatile("s_waitcnt vmcnt(0)" ::: "memory");
      __syncthreads();
      mfma_pass(As, Ws, acc);
      __syncthreads();
    }
    store_tile_f16(acc, qk, 256, nullptr, nullptr, m0, n0, 0);
  }
}

// stage 7: pure GEMM — gf = cf@Wfast, gs = cs@Wslow (A = transformed wgfs), soma = xh@Wsoma
__global__ __launch_bounds__(256,4) void k_gemm_s7(
    const _Float16* __restrict__ cfs, const _Float16* __restrict__ xh,
    const _Float16* __restrict__ wall,
    const float* __restrict__ bf, const float* __restrict__ bs, const float* __restrict__ bso,
    _Float16* __restrict__ gfb, _Float16* __restrict__ gsb, _Float16* __restrict__ somab)
{
  __shared__ _Float16 As[128*64];
  __shared__ _Float16 Bs[128*64];
  const size_t per = (size_t)C_*C_;
  floatx4 acc[4][4] = {};
  int m0 = blockIdx.x * 128;
  int s = blockIdx.y / 6, nt = (blockIdx.y % 6) * 128;
  const _Float16* Asrc = (s == 0) ? cfs : (s == 1 ? cfs + C_ : xh);
  int lda = (s == 2) ? C_ : K2_;
  const _Float16* Bsrc = wall + (size_t)(s+1)*per;   // Wfast / Wslow / Wsoma
  for (int k0 = 0; k0 < C_; k0 += 64){
    stage_tile(Asrc, lda, m0, k0, As);
    stage_tile(Bsrc, C_, nt, k0, Bs);
    asm volatile("s_waitcnt vmcnt(0)" ::: "memory");
    __syncthreads();
    mfma_pass(As, Bs, acc);
    __syncthreads();
  }
  if (s == 2)      store_tile_f16(acc, somab, C_, bso, nullptr, m0, nt, 1);
  else if (s == 1) store_tile_f16(acc, gsb,  C_, bs,  nullptr, m0, nt, 2);
  else             store_tile_f16(acc, gfb,  C_, bf,  nullptr, m0, nt, 2);
}

// ---------------- score (544 blocks) + fs_p1 (512 blocks, 2 chunks each) ----------------
#define SLDK 104
__global__ __launch_bounds__(256,3) void k_score_fs(
    const _Float16* __restrict__ qk, unsigned* __restrict__ cgE,
    const _Float16* __restrict__ xp, const _Float16* __restrict__ wgfs,
    const float* __restrict__ tf, const float* __restrict__ ts,
    float* __restrict__ Sf, float* __restrict__ Ss)
{
  __shared__ _Float16 Qs[128*SLDK];
  __shared__ _Float16 Ks[128*SLDK];
  __shared__ float sred[256];
  int idx = blockIdx.x;
  int tid = threadIdx.x;
  if (idx >= 544){
    // ---- fs_p1: 2 chunks/block, 8 cols/thread, half8 loads ----
    if (tid >= 192) return;
    int half = tid / 96, ct = tid - half*96;
    int f = (idx - 544)*2 + half;            // chunk 0..1023
    float af = expf(-log1pf(expf(tf[0])));
    float as = expf(-log1pf(expf(ts[0])));
    int b = f >> 8, ch = f & (NCH_-1);
    int t0 = b*T_ + ch*CK_;
    int c0 = ct*8;
    float fv[8] = {0,0,0,0,0,0,0,0};
    float sv[8] = {0,0,0,0,0,0,0,0};
    #pragma unroll
    for (int t = 0; t < CK_; ++t){
      half8 p  = *(const half8*)(xp + (size_t)(t0+t)*C_ + c0);
      half8 wf = *(const half8*)(wgfs + (size_t)(t0+t)*K2_ + c0);
      half8 ws = *(const half8*)(wgfs + (size_t)(t0+t)*K2_ + C_ + c0);
      #pragma unroll
      for (int i = 0; i < 8; ++i){
        fv[i] = af*fv[i] + (float)p[i]*(float)wf[i];
        sv[i] = as*sv[i] + (float)p[i]*(float)ws[i];
      }
    }
    float4 fa = { fv[0],fv[1],fv[2],fv[3] }, fb = { fv[4],fv[5],fv[6],fv[7] };
    float4 sa = { sv[0],sv[1],sv[2],sv[3] }, sb = { sv[4],sv[5],sv[6],sv[7] };
    *(float4*)(Sf + (size_t)f*C_ + c0)     = fa;
    *(float4*)(Sf + (size_t)f*C_ + c0 + 4) = fb;
    *(float4*)(Ss + (size_t)f*C_ + c0)     = sa;
    *(float4*)(Ss + (size_t)f*C_ + c0 + 4) = sb;
    return;
  }
  // ---- score ----
  int b = idx / 136;
  int p = idx - b*136;
  int ti = (int)((sqrtf(8.f*p + 1.f) - 1.f)*0.5f);
  while ((ti+1)*(ti+2)/2 <= p) ++ti;
  while (ti*(ti+1)/2 > p) --ti;
  int sj = p - ti*(ti+1)/2;

  const _Float16* qg = qk + (size_t)(b*T_ + ti*128)*256;
  const _Float16* kg = qk + (size_t)(b*T_ + sj*128)*256 + 96;
  #pragma unroll
  for (int r = 0; r < 6; ++r){
    int ci = tid + r*256;
    int row = ci / 12, kp = ci % 12;
    *(uint4*)(&Qs[row*SLDK + kp*8]) = *(const uint4*)(qg + (size_t)row*256 + kp*8);
    *(uint4*)(&Ks[row*SLDK + kp*8]) = *(const uint4*)(kg + (size_t)row*256 + kp*8);
  }
  __syncthreads();

  int wave = tid >> 6, lane = tid & 63;
  int wr = wave >> 1, wc = wave & 1;
  int lr = lane & 15, lq = lane >> 4;
  floatx4 acc[4][4] = {};
  #pragma unroll
  for (int ks = 0; ks < 3; ++ks){
    half8 fa[4], fb[4];
    #pragma unroll
    for (int i = 0; i < 4; ++i){
      fa[i] = *(const half8*)(&Qs[(wr*64 + i*16 + lr)*SLDK + ks*32 + lq*8]);
      fb[i] = *(const half8*)(&Ks[(wc*64 + i*16 + lr)*SLDK + ks*32 + lq*8]);
    }
    #pragma unroll
    for (int i = 0; i < 4; ++i)
      #pragma unroll
      for (int j = 0; j < 4; ++j)
        acc[i][j] = __builtin_amdgcn_mfma_f32_16x16x32_f16(fa[i], fb[j], acc[i][j], 0, 0, 0);
  }
  const float scale = 0.10206207f;   // 96^-0.5
  #pragma unroll
  for (int i = 0; i < 4; ++i){
    #pragma unroll
    for (int r = 0; r < 4; ++r){
      int row64 = i*16 + lq*4 + r;
      int tg = ti*128 + wr*64 + row64;
      float v = -3.0e38f;
      #pragma unroll
      for (int j = 0; j < 4; ++j){
        int sg = sj*128 + wc*64 + j*16 + lr;
        if (sg <= tg) v = fmaxf(v, acc[i][j][r]*scale);
      }
      #pragma unroll
      for (int off = 1; off < 16; off <<= 1) v = fmaxf(v, __shfl_xor(v, off, 16));
      if (lr == 0) sred[wr*128 + wc*64 + row64] = v;
    }
  }
  __syncthreads();
  if (wc == 0 && lane < 64){
    int row64 = lane;
    float v = fmaxf(sred[wr*128 + row64], sred[wr*128 + 64 + row64]);
    int tg = ti*128 + wr*64 + row64;
    atomicMax(&cgE[(size_t)b*T_ + tg], enc_max(v));
  }
}

// ---------------- fused blend + soma-mul + LayerNorm ----------------
// 2 rows/wave (32 lanes/row, 24 cols/lane) -> half8 (16B) loads.
__global__ __launch_bounds__(256) void k_ln(const _Float16* __restrict__ gfb,
                                            const _Float16* __restrict__ gsb,
                                            const _Float16* __restrict__ somab,
                                            const float* __restrict__ blendr,
                                            const float* __restrict__ g, const float* __restrict__ be,
                                            float* __restrict__ out){
  int wave = threadIdx.x >> 6, lane = threadIdx.x & 63;
  int half = lane >> 5, l32 = lane & 31;
  int row = blockIdx.x*8 + wave*2 + half;
  float bl = sigm(blendr[0]);
  size_t rb = (size_t)row*C_;
  float v[24];
  float s = 0.f, ss = 0.f;
  #pragma unroll
  for (int w2 = 0; w2 < 3; ++w2){
    size_t o = rb + w2*256 + l32*8;
    half8 gf8 = *(const half8*)(gfb + o);
    half8 gs8 = *(const half8*)(gsb + o);
    half8 so8 = *(const half8*)(somab + o);
    #pragma unroll
    for (int i = 0; i < 8; ++i){
      float gf = (float)gf8[i], gs = (float)gs8[i], so = (float)so8[i];
      float y = so * (gf + bl*(gs - gf));
      v[w2*8 + i] = y; s += y; ss += y*y;
    }
  }
  #pragma unroll
  for (int off = 1; off < 32; off <<= 1){ s += __shfl_xor(s, off, 32); ss += __shfl_xor(ss, off, 32); }
  float mu  = s * (1.f/C_);
  float var = ss * (1.f/C_) - mu*mu;
  float inv = rsqrtf(var + 1e-5f);
  #pragma unroll
  for (int w2 = 0; w2 < 3; ++w2){
    int c0 = w2*256 + l32*8;
    float4 oa, ob;
    oa.x = (v[w2*8+0]-mu)*inv*g[c0+0] + be[c0+0];
    oa.y = (v[w2*8+1]-mu)*inv*g[c0+1] + be[c0+1];
    oa.z = (v[w2*8+2]-mu)*inv*g[c0+2] + be[c0+2];
    oa.w = (v[w2*8+3]-mu)*inv*g[c0+3] + be[c0+3];
    ob.x = (v[w2*8+4]-mu)*inv*g[c0+4] + be[c0+4];
    ob.y = (v[w2*8+5]-mu)*inv*g[c0+5] + be[c0+5];
    ob.z = (v[w2*8+6]-mu)*inv*g[c0+6] + be[c0+6];
    ob.w = (v[w2*8+7]-mu)*inv*g[c0+7] + be[c0+7];
    *(float4*)(out + rb + c0)     = oa;
    *(float4*)(out + rb + c0 + 4) = ob;
  }
}

// ---------------- launch ----------------
extern "C" void kernel_launch(void* const* d_in, const int* in_sizes, int n_in,
                              void* d_out, int out_size, void* d_ws, size_t ws_size,
                              hipStream_t stream){
  (void)in_sizes; (void)n_in; (void)out_size;
  const float* x        = (const float*)d_in[0];
  const float* tau_gate = (const float*)d_in[1];
  const float* tau_fast = (const float*)d_in[2];
  const float* tau_slow = (const float*)d_in[3];
  const float* Wp   = (const float*)d_in[4];  const float* bp    = (const float*)d_in[5];
  const float* Wxf  = (const float*)d_in[6];  const float* bxf   = (const float*)d_in[7];
  const float* Wxs  = (const float*)d_in[8];  const float* bxs   = (const float*)d_in[9];
  const float* Wcf  = (const float*)d_in[10]; const float* Wcs   = (const float*)d_in[11];
  const float* Wq   = (const float*)d_in[12]; const float* Wk    = (const float*)d_in[13];
  const float* Wfast= (const float*)d_in[14]; const float* bfast = (const float*)d_in[15];
  const float* Wslow= (const float*)d_in[16]; const float* bslow = (const float*)d_in[17];
  const float* Wsoma= (const float*)d_in[18]; const float* bsoma = (const float*)d_in[19];
  const float* Wanc = (const float*)d_in[20]; const float* banc  = (const float*)d_in[21];
  const float* ascl = (const float*)d_in[22]; const float* blendr= (const float*)d_in[23];
  const float* lng  = (const float*)d_in[24]; const float* lnb   = (const float*)d_in[25];
  float* out = (float*)d_out;

  char* w = (char*)d_ws;
  auto alloc = [&](size_t bytes)->void*{
    void* p = (void*)w; w += (bytes + 255) & ~(size_t)255; return p;
  };
  _Float16* xh    = (_Float16*)alloc((size_t)M_*C_*2);
  _Float16* wall  = (_Float16*)alloc((size_t)8*C_*C_*2);
  _Float16* wqk   = (_Float16*)alloc((size_t)256*C_*2);
  _Float16* xph   = (_Float16*)alloc((size_t)M_*C_*2);
  _Float16* wgfs  = (_Float16*)alloc((size_t)M_*K2_*2);
  _Float16* qk    = (_Float16*)alloc((size_t)M_*256*2);
  _Float16* gfb   = (_Float16*)alloc((size_t)M_*C_*2);
  _Float16* gsb   = (_Float16*)alloc((size_t)M_*C_*2);
  _Float16* somab = (_Float16*)alloc((size_t)M_*C_*2);
  unsigned* cgE   = (unsigned*)alloc((size_t)M_*4);
  float* Sg = (float*)alloc((size_t)B_*NCH_*C_*4);
  float* Hg = (float*)alloc((size_t)B_*NCH_*C_*4);
  float* Ss = (float*)alloc((size_t)B_*NCH_*C_*4);
  float* Hs = (float*)alloc((size_t)B_*NCH_*C_*4);
  float* dlt = (float*)alloc((size_t)B_*C_*4);
  // aliases (stream-ordered reuse):
  _Float16* gate = gfb;  // gate consumed by s3 (L4) before s7 (L7) writes gfb
  float* Sf = Sg;        // Sg consumed by prep's p2_gate (L2) before score_fs (L5) writes Sf
  float* Hf = Hg;        // Hg consumed by gate_p3 (L3) before p2_fs (L6) writes Hf
  if ((size_t)(w - (char*)d_ws) > ws_size) return;

  // L1: cast x -> xh + gate chunk sums
  k_castx<<<B_*NCH_, 192, 0, stream>>>(x, tau_gate, xh, Sg);
  // L2: weights, cgE, anchors, gate chunk-prefix (2-level scan, hides under bulk casts)
  k_prep<<<NB3, 256, 0, stream>>>(x, Wp, Wfast, Wslow, Wsoma, Wxf, Wxs, Wcf, Wcs, Wq, Wk,
                                  Wanc, banc, ascl, tau_gate, Sg, wall, wqk, cgE, Hg, dlt);
  // L3: gate EMA stream -> gate buffer (2 chunks/block, half8)
  k_gate_p3<<<B_*NCH_/2, 192, 0, stream>>>(xh, Hg, tau_gate, gate);
  // L4: stage 3 (xp + wg split-K + q||k), clean 2-barrier K-loop
  k_gemm_s3<<<dim3(M_/128, 20), 256, 0, stream>>>(xh, gate, wall, wqk,
                                                  bp, bxf, bxs, xph, wgfs, qk);
  // L5: causal max score + fs chunk sums (2 chunks/block, half8)
  k_score_fs<<<544 + B_*NCH_/2, 256, 0, stream>>>(qk, cgE, xph, wgfs, tau_fast, tau_slow, Sf, Ss);
  // L6: fast/slow chunk-prefix (2-level scan, 384 blocks)
  k_p2_fs<<<2*B_*48, 256, 0, stream>>>(Sf, Ss, Hf, Hs, tau_fast, tau_slow);
  // L6.5: fs EMA pass3 — transform wgfs in place to cf||cs (2 chunks/block, half8)
  k_fs_p3<<<B_*NCH_/2, 192, 0, stream>>>(xph, wgfs, Hf, Hs, tau_fast, tau_slow, cgE, dlt);
  // L7: stage 7 — pure 3-GEMM (gf, gs, soma)
  k_gemm_s7<<<dim3(M_/128, 18), 256, 0, stream>>>(wgfs, xh, wall,
                                                  bfast, bslow, bsoma, gfb, gsb, somab);
  // L8: fused blend + mul + LN (2 rows/wave, half8)
  k_ln<<<M_/8, 256, 0, stream>>>(gfb, gsb, somab, blendr, lng, lnb, out);
}